// Round 10
// baseline (231.872 us; speedup 1.0000x reference)
//
#include <hip/hip_runtime.h>

// Problem constants (from setup_inputs)
constexpr int NROIS = 2000;
constexpr int Hh = 100, Ww = 100, Cc = 256;
constexpr int CH = 7, CW = 7;
constexpr int NRG    = NROIS * CH;     // 14,000 roi-rows (row-groups)
constexpr int NBAND  = 25;             // y-bands of 4 rows (stage 5 = 4+1 halo)
constexpr int NBIN   = 8 * NBAND;      // 200 (image, band) bins
constexpr int NSLICE = 8;              // channel slices of 32

constexpr int ROW_BYTES = Ww * Cc * 4;            // 102,400 B per fm row
constexpr int PIX_BYTES = Cc * 4;                 // 1,024 B per fm pixel
constexpr int IMG_BYTES = Hh * ROW_BYTES;         // 10,240,000 B per image
constexpr int OUTROI_BYTES = CH * CW * PIX_BYTES; // 50,176 B per roi output

typedef float floatx4 __attribute__((ext_vector_type(4)));

// ---------------------------------------------------------------------------
// Shared banding function — used by BOTH count and scatter so bin assignment
// is bit-identical (explicit fmaf; no reassociable expressions).
// Record: g[13:0] | ty[20:14] | by[27:21] | validy[28].
// ---------------------------------------------------------------------------
__device__ __forceinline__ void row_band(const float* __restrict__ rois, int g,
                                         int& bin, unsigned& rec)
{
    int n = g / 7, i = g - n * 7;
    const float* r = rois + (size_t)n * 5;
    int   b  = (int)r[0];
    float y1 = r[2] / 100.f, y2 = r[4] / 100.f;     // reference math order
    float y0 = y1 * 99.f;
    float sy = (y2 - y1) * 99.f / 6.f;
    float in_y = fmaf((float)i, sy, y0);
    int vy = (in_y >= 0.f && in_y <= 99.f) ? 1 : 0;
    int ty = max(0, min(99, (int)floorf(in_y)));
    int by = max(0, min(99, (int)ceilf(in_y)));
    bin = b * NBAND + (ty >> 2);
    rec = (unsigned)g | ((unsigned)ty << 14) | ((unsigned)by << 21)
        | ((unsigned)vy << 28);
}

// -------- prepass 1: per-ROI params + bin counts ---------------------------
__global__ __launch_bounds__(256) void k_count(
    const float* __restrict__ rois, float* __restrict__ params,
    int* __restrict__ cnt)
{
    int t = blockIdx.x * 256 + threadIdx.x;
    int stride = gridDim.x * 256;
    for (int n = t; n < NROIS; n += stride) {
        const float* r = rois + (size_t)n * 5;
        float x1 = r[1] / 100.f, y1 = r[2] / 100.f;
        float x2 = r[3] / 100.f, y2 = r[4] / 100.f;
        float* P = params + (size_t)n * 8;
        P[0] = y1 * 99.f;                  // y0
        P[1] = (y2 - y1) * 99.f / 6.f;     // sy
        P[2] = x1 * 99.f;                  // x0
        P[3] = (x2 - x1) * 99.f / 6.f;     // sx
        ((int*)P)[5] = n * OUTROI_BYTES;   // out byte base
    }
    for (int g = t; g < NRG; g += stride) {
        int bin; unsigned rec;
        row_band(rois, g, bin, rec);
        atomicAdd(&cnt[bin], 1);
    }
}

// -------- prepass 2: exclusive prefix over 200 bins ------------------------
__global__ void k_prefix(int* __restrict__ binoffs, int* __restrict__ runoffs)
{
    if (threadIdx.x == 0 && blockIdx.x == 0) {
        int s = 0;
        for (int k = 0; k < NBIN; ++k) {
            int c = binoffs[k];
            binoffs[k] = s; runoffs[k] = s; s += c;
        }
        binoffs[NBIN] = s;
    }
}

// -------- prepass 3: scatter row-group records into bins -------------------
__global__ __launch_bounds__(256) void k_scatter(
    const float* __restrict__ rois, int* __restrict__ runoffs,
    unsigned* __restrict__ binned)
{
    int t = blockIdx.x * 256 + threadIdx.x;
    int stride = gridDim.x * 256;
    for (int g = t; g < NRG; g += stride) {
        int bin; unsigned rec;
        row_band(rois, g, bin, rec);
        int pos = atomicAdd(&runoffs[bin], 1);
        binned[pos] = rec;
    }
}

// ---------------------------------------------------------------------------
// Main kernel: INVERTED LOOP. Block = (image, y-band, channel-slice).
// Stage 5 fm rows x 100 px x 32 ch (64,000 B) into LDS with coalesced
// streaming reads, then serve every sample whose ty lies in this band from
// LDS. Global logical reads drop 392 MB -> ~102 MB (the measured limiter is
// per-CU line-request concurrency; this cuts line requests ~4x and converts
// the 4.9x cross-ROI reuse into LDS hits). Thread layout in sample loop:
// 32 sample-slots x 8 lanes; each lane reads/writes float4 (ds_read_b128,
// banks balanced: slot lanes cover banks 4c..4c+3, 8 slots tile all 32).
// ---------------------------------------------------------------------------
__global__ __launch_bounds__(256) void k_main(
    const char* __restrict__ fm,       // [8,100,100,256] fp32 as bytes
    const float* __restrict__ params,  // [2000][8]
    const int* __restrict__ binoffs,   // [201]
    const unsigned* __restrict__ binned, // [14000] records
    char* __restrict__ out)            // [2000,7,7,256] fp32 as bytes
{
    __shared__ float lds[5 * 100 * 32];   // 64,000 B -> 2 blocks/CU

    int bin  = blockIdx.x >> 3;           // 0..199
    int s    = blockIdx.x & 7;            // channel slice
    int b    = bin / NBAND;
    int band = bin - b * NBAND;
    int r0   = band * 4;
    int t    = threadIdx.x;

    // ---- stage: 4000 float4 = 5 rows x 100 px x 8 quads --------------------
    const char* src = fm + (size_t)b * IMG_BYTES + s * 128;
    for (int idx = t; idx < 4000; idx += 256) {
        int cq  = idx & 7;
        int pr  = idx >> 3;
        int px  = pr % 100;
        int row = pr / 100;                    // 0..4
        int rr  = min(r0 + row, 99);           // halo row clamp (content unused)
        floatx4 v = *(const floatx4*)(src + rr * ROW_BYTES + px * PIX_BYTES + cq * 16);
        *(floatx4*)&lds[(size_t)idx * 4] = v;
    }
    __syncthreads();

    // ---- serve samples ------------------------------------------------------
    int base  = binoffs[bin];
    int total = (binoffs[bin + 1] - base) * 7;
    int c4    = t & 7;                     // float4 index within 32-ch slice
    int slot  = t >> 3;                    // 32 sample-slots

    for (int ss = slot; ss < total; ss += 32) {
        int rgi = ss / 7, j = ss - rgi * 7;
        unsigned rec = binned[base + rgi];
        int g  = rec & 0x3FFF;
        int ty = (rec >> 14) & 127;
        int by = (rec >> 21) & 127;
        int vy = (rec >> 28) & 1;
        int n = g / 7, i = g - n * 7;

        const float* P = params + (size_t)n * 8;
        float y0 = P[0], sy = P[1], x0 = P[2], sx = P[3];
        int outb = ((const int*)P)[5];

        float in_y = fmaf((float)i, sy, y0);
        float in_x = fmaf((float)j, sx, x0);
        bool valid = vy && (in_x >= 0.f) && (in_x <= 99.f);

        float ly = in_y - (float)ty;       // == frac(in_y) for valid rows
        int tx = max(0, min(99, (int)floorf(in_x)));
        int bx = max(0, min(99, (int)ceilf(in_x)));
        float lx = in_x - (float)tx;       // == frac(in_x) for valid cols
        int tyo = ty - r0, byo = by - r0;  // in [0,4] by bin construction

        floatx4 tl = *(const floatx4*)&lds[((tyo * 100 + tx) * 8 + c4) * 4];
        floatx4 tr = *(const floatx4*)&lds[((tyo * 100 + bx) * 8 + c4) * 4];
        floatx4 bl = *(const floatx4*)&lds[((byo * 100 + tx) * 8 + c4) * 4];
        floatx4 br = *(const floatx4*)&lds[((byo * 100 + bx) * 8 + c4) * 4];

        floatx4 top = tl + (tr - tl) * lx;
        floatx4 bot = bl + (br - bl) * lx;
        floatx4 o   = top + (bot - top) * ly;
        o = valid ? o : (floatx4)0.f;

        *(floatx4*)(out + outb + (i * 7 + j) * PIX_BYTES + s * 128 + c4 * 16) = o;
    }
}

extern "C" void kernel_launch(void* const* d_in, const int* in_sizes, int n_in,
                              void* d_out, int out_size, void* d_ws, size_t ws_size,
                              hipStream_t stream) {
    const float* fm   = (const float*)d_in[0];   // [8,100,100,256] fp32
    const float* rois = (const float*)d_in[1];   // [2000,5] fp32
    char* out = (char*)d_out;                    // [2000,7,7,256] fp32

    char* ws = (char*)d_ws;                      // ~122 KB used
    float*    params  = (float*)ws;              // 64,000 B
    int*      binoffs = (int*)(ws + 64000);      // 804 B (counts -> prefix)
    int*      runoffs = (int*)(ws + 64832);      // 800 B
    unsigned* binned  = (unsigned*)(ws + 65664); // 56,000 B

    hipMemsetAsync(binoffs, 0, (NBIN + 1) * sizeof(int), stream);
    k_count  <<<8, 256, 0, stream>>>(rois, params, binoffs);
    k_prefix <<<1, 64, 0, stream>>>(binoffs, runoffs);
    k_scatter<<<8, 256, 0, stream>>>(rois, runoffs, binned);
    k_main   <<<NBIN * NSLICE, 256, 0, stream>>>((const char*)fm, params,
                                                 binoffs, binned, out);
}